// Round 1
// baseline (12395.616 us; speedup 1.0000x reference)
//
#include <hip/hip_runtime.h>
#include <hip/hip_bf16.h>

#define V_SZ 100000
#define E_SZ 128
#define H_SZ 512
#define L_SZ 9
#define B_SZ 64
#define T_SZ 512
#define G4   (4*H_SZ)

#define LOGITS_N (B_SZ*T_SZ*L_SZ)   // 294912
#define HS_BYTES ((size_t)B_SZ*T_SZ*H_SZ*2)  // 33554432

typedef short bf16x8 __attribute__((ext_vector_type(8)));
typedef float f32x4  __attribute__((ext_vector_type(4)));

static __device__ __forceinline__ unsigned short f2bf(float x){
  unsigned int u = __builtin_bit_cast(unsigned int, x);
  unsigned int r = (u + 0x7fffu + ((u >> 16) & 1u)) >> 16;
  return (unsigned short)r;
}
static __device__ __forceinline__ float bf2f(unsigned short b){
  unsigned int u = ((unsigned int)b) << 16;
  return __builtin_bit_cast(float, u);
}
static __device__ __forceinline__ float sig_f(float x){
  return 1.f / (1.f + __expf(-x));
}
static __device__ __forceinline__ float tanh_f(float x){
  float a = fabsf(x);
  float e = __expf(-2.f * a);
  float t = (1.f - e) / (1.f + e);
  return copysignf(t, x);
}

// ---------------- lens ----------------
__global__ void k_lens(const int* __restrict__ text, float* __restrict__ out_lens){
  int b = blockIdx.x;
  int c = 0;
  for (int t = threadIdx.x; t < T_SZ; t += 256)
    c += (text[b*T_SZ + t] != 0);
  for (int off = 32; off; off >>= 1) c += __shfl_down(c, off, 64);
  __shared__ int sred[4];
  int w = threadIdx.x >> 6;
  if ((threadIdx.x & 63) == 0) sred[w] = c;
  __syncthreads();
  if (threadIdx.x == 0)
    out_lens[b] = (float)(sred[0] + sred[1] + sred[2] + sred[3]);
}

// ---------------- fused embed + xg + LSTM recurrence ----------------
__global__ __launch_bounds__(256, 1)
void k_lstm(const int* __restrict__ text, const float* __restrict__ embed,
            const float* __restrict__ Wx, const float* __restrict__ Wh,
            const float* __restrict__ bias, unsigned short* __restrict__ hs,
            int* __restrict__ cnt)
{
  const int g   = blockIdx.x & 7;     // group (intended XCD)
  const int j   = blockIdx.x >> 3;    // 0..31 block-in-group
  const int n0  = j * 16;             // owned h-columns [n0, n0+16)
  const int tid = threadIdx.x;
  const int w   = tid >> 6;           // wave = gate quadrant (i,f,cg,o)
  const int lane = tid & 63;
  const int q   = lane >> 4;
  const int l16 = lane & 15;

  __shared__ unsigned short h_lds[16*512];   // 16 KB, XOR-swizzled, rows 8-15 zero
  __shared__ unsigned short x_lds[16*128];   // 4 KB, XOR-swizzled, rows 8-15 zero
  __shared__ float gate_lds[4][8][16];       // 2 KB

  for (int i = tid; i < 16*512; i += 256) h_lds[i] = 0;
  for (int i = tid; i < 16*128; i += 256) x_lds[i] = 0;

  // Preload weight B-frags into registers (bf16). B elem jj of k-chunk kk:
  // W[(kk*32 + q*8 + jj)][gcol] — same (q,jj)->k map as the A-side LDS reads.
  const int gcol = w * H_SZ + n0 + l16;
  bf16x8 Whf[16];
#pragma unroll
  for (int kk = 0; kk < 16; ++kk){
    bf16x8 v;
#pragma unroll
    for (int jj = 0; jj < 8; ++jj)
      v[jj] = (short)f2bf(Wh[(long)(kk*32 + q*8 + jj)*G4 + gcol]);
    Whf[kk] = v;
  }
  bf16x8 Wxf[4];
#pragma unroll
  for (int kk = 0; kk < 4; ++kk){
    bf16x8 v;
#pragma unroll
    for (int jj = 0; jj < 8; ++jj)
      v[jj] = (short)f2bf(Wx[(long)(kk*32 + q*8 + jj)*G4 + gcol]);
    Wxf[kk] = v;
  }
  const float biasv = bias[gcol];

  float cstate = 0.f;                 // per-thread c for tid<128: (r128, n128)
  const int r128 = tid >> 4;          // batch row 0..7 (valid when tid<128)
  const int n128 = tid & 15;

  __syncthreads();

  for (int t = 0; t < T_SZ; ++t){
    // ---- stage x_t (embed gather -> bf16 -> swizzled LDS); safe vs prev step ----
    {
      int xr = tid >> 5;                    // 0..7 (batch row)
      int c4 = (tid & 31) * 4;              // f32 column
      int idx = text[(g*8 + xr)*T_SZ + t];
      const float4 xv = *(const float4*)(embed + (long)idx*E_SZ + c4);
      int cb = c4 * 2;                      // byte col
      unsigned short* p = (unsigned short*)((char*)x_lds + xr*256 + (cb ^ (xr << 4)));
      p[0] = f2bf(xv.x); p[1] = f2bf(xv.y); p[2] = f2bf(xv.z); p[3] = f2bf(xv.w);
    }

    if (t > 0){
      if (tid == 0){
        int it = 0;
        while (__hip_atomic_load(&cnt[g*T_SZ + t - 1], __ATOMIC_ACQUIRE,
                                 __HIP_MEMORY_SCOPE_AGENT) < 32 && it < (1 << 24)){
          ++it;
          __builtin_amdgcn_s_sleep(2);
        }
      }
      __syncthreads();
      // ---- stage h_{t-1}: 8 rows x 512 bf16 from global, swizzled into LDS ----
#pragma unroll
      for (int c = 0; c < 2; ++c){
        int idx2 = tid*2 + c;               // 0..511 chunks of 8 bf16
        int hr   = idx2 >> 6;               // 0..7
        int k8   = (idx2 & 63) * 8;
        uint4 hv = *(const uint4*)(hs + ((long)(g*8 + hr)*T_SZ + (t-1))*H_SZ + k8);
        int cb = k8 * 2;
        *(uint4*)((char*)h_lds + hr*1024 + (cb ^ (hr << 4))) = hv;
      }
    }
    __syncthreads();

    // ---- MFMA: C = x_t @ Wx  (+ h_{t-1} @ Wh) ----
    f32x4 acc0 = {0.f,0.f,0.f,0.f}, acc1 = {0.f,0.f,0.f,0.f};
#pragma unroll
    for (int kk = 0; kk < 4; ++kk){
      bf16x8 a = *(const bf16x8*)((const char*)x_lds + l16*256 + ((kk*64 + q*16) ^ (l16 << 4)));
      if (kk & 1) acc1 = __builtin_amdgcn_mfma_f32_16x16x32_bf16(a, Wxf[kk], acc1, 0, 0, 0);
      else        acc0 = __builtin_amdgcn_mfma_f32_16x16x32_bf16(a, Wxf[kk], acc0, 0, 0, 0);
    }
    if (t > 0){
#pragma unroll
      for (int kk = 0; kk < 16; ++kk){
        bf16x8 a = *(const bf16x8*)((const char*)h_lds + l16*1024 + ((kk*64 + q*16) ^ (l16 << 4)));
        if (kk & 1) acc1 = __builtin_amdgcn_mfma_f32_16x16x32_bf16(a, Whf[kk], acc1, 0, 0, 0);
        else        acc0 = __builtin_amdgcn_mfma_f32_16x16x32_bf16(a, Whf[kk], acc0, 0, 0, 0);
      }
    }
    // C/D layout: col = lane&15, row = (lane>>4)*4 + reg  (rows 0..7 valid)
#pragma unroll
    for (int rg = 0; rg < 4; ++rg){
      int row = q*4 + rg;
      if (row < 8) gate_lds[w][row][l16] = acc0[rg] + acc1[rg] + biasv;
    }
    __syncthreads();

    // ---- gates -> (c,h); write h slice to global ----
    if (tid < 128){
      float gi = gate_lds[0][r128][n128];
      float gf = gate_lds[1][r128][n128];
      float gc = gate_lds[2][r128][n128];
      float go = gate_lds[3][r128][n128];
      float si = sig_f(gi), sf = sig_f(gf), so = sig_f(go);
      cstate = sf*cstate + si*tanh_f(gc);
      float hv = so * tanh_f(cstate);
      hs[((long)(g*8 + r128)*T_SZ + t)*H_SZ + n0 + n128] = f2bf(hv);
    }
    __threadfence();       // each storing thread makes its h writes agent-visible
    __syncthreads();
    if (tid == 0)
      __hip_atomic_fetch_add(&cnt[g*T_SZ + t], 1, __ATOMIC_RELEASE,
                             __HIP_MEMORY_SCOPE_AGENT);
  }
}

// ---------------- logits = hs @ Wd + bd ----------------
__global__ void k_logits(const unsigned short* __restrict__ hs,
                         const float* __restrict__ Wd, const float* __restrict__ bd,
                         float* __restrict__ out)
{
  __shared__ float wd_s[H_SZ*L_SZ];
  __shared__ float bd_s[L_SZ];
  for (int i = threadIdx.x; i < H_SZ*L_SZ; i += 128) wd_s[i] = Wd[i];
  if (threadIdx.x < L_SZ) bd_s[threadIdx.x] = bd[threadIdx.x];
  __syncthreads();

  long row = (long)blockIdx.x*128 + threadIdx.x;   // 0..32767
  const unsigned short* hp = hs + row*H_SZ;
  float acc[9];
#pragma unroll
  for (int jj = 0; jj < 9; ++jj) acc[jj] = 0.f;
  for (int k = 0; k < H_SZ; k += 8){
    uint4 v = *(const uint4*)(hp + k);
    const unsigned short* u = (const unsigned short*)&v;
#pragma unroll
    for (int l = 0; l < 8; ++l){
      float hf = bf2f(u[l]);
#pragma unroll
      for (int jj = 0; jj < 9; ++jj)
        acc[jj] = fmaf(hf, wd_s[(k + l)*L_SZ + jj], acc[jj]);
    }
  }
  float* op = out + row*L_SZ;
#pragma unroll
  for (int jj = 0; jj < 9; ++jj) op[jj] = acc[jj] + bd_s[jj];
}

// ---------------- CRF: score + forward algorithm ----------------
__global__ void k_crf(const float* __restrict__ logits, const int* __restrict__ labels,
                      const float* __restrict__ trans, const float* __restrict__ lensf,
                      float* __restrict__ out_ll)
{
  int b = blockIdx.x;
  int lane = threadIdx.x;             // 64 threads = 1 wave
  int len = (int)lensf[b];
  const float* lg  = logits + (long)b*T_SZ*L_SZ;
  const int*   lab = labels + b*T_SZ;

  // score = masked unary + masked binary
  float s = 0.f;
  for (int t = lane; t < T_SZ; t += 64){
    if (t < len){
      s += lg[t*L_SZ + lab[t]];
      if (t >= 1) s += trans[lab[t-1]*L_SZ + lab[t]];
    }
  }
  for (int off = 32; off; off >>= 1) s += __shfl_down(s, off, 64);

  // forward recursion, lanes 0..8 hold alpha[j]
  float tr[9];
#pragma unroll
  for (int i = 0; i < 9; ++i) tr[i] = (lane < 9) ? trans[i*L_SZ + lane] : 0.f;
  float alpha = (lane < 9) ? lg[lane] : -1e30f;

  for (int t = 1; t < T_SZ; ++t){
    float tmp[9];
    float m = -1e30f;
#pragma unroll
    for (int i = 0; i < 9; ++i){
      float ai = __shfl(alpha, i, 64);
      tmp[i] = ai + tr[i];
      m = fmaxf(m, tmp[i]);
    }
    float e = 0.f;
#pragma unroll
    for (int i = 0; i < 9; ++i) e += __expf(tmp[i] - m);
    float lgv = (lane < 9) ? lg[t*L_SZ + lane] : 0.f;
    float nv = m + __logf(e) + lgv;
    if (t < len && lane < 9) alpha = nv;
  }

  // log_norm = logsumexp over lanes 0..8
  float mm = (lane < 9) ? alpha : -1e30f;
  for (int off = 8; off; off >>= 1) mm = fmaxf(mm, __shfl_down(mm, off, 64));
  mm = __shfl(mm, 0, 64);
  float ee = (lane < 9) ? __expf(alpha - mm) : 0.f;
  for (int off = 8; off; off >>= 1) ee += __shfl_down(ee, off, 64);
  if (lane == 0) out_ll[b] = s - (mm + __logf(ee));
}

extern "C" void kernel_launch(void* const* d_in, const int* in_sizes, int n_in,
                              void* d_out, int out_size, void* d_ws, size_t ws_size,
                              hipStream_t stream)
{
  const int*   text   = (const int*)  d_in[0];
  const int*   labels = (const int*)  d_in[1];
  const float* embed  = (const float*)d_in[2];
  const float* Wx     = (const float*)d_in[3];
  const float* Wh     = (const float*)d_in[4];
  const float* bias   = (const float*)d_in[5];
  const float* Wd     = (const float*)d_in[6];
  const float* bd     = (const float*)d_in[7];
  const float* trans  = (const float*)d_in[8];

  float* out        = (float*)d_out;
  float* out_logits = out;
  float* out_lens   = out + LOGITS_N;
  float* out_ll     = out + LOGITS_N + B_SZ;

  unsigned short* hs = (unsigned short*)d_ws;
  int* cnt = (int*)((char*)d_ws + HS_BYTES);

  hipMemsetAsync(cnt, 0, 8*T_SZ*sizeof(int), stream);
  k_lens  <<<B_SZ, 256, 0, stream>>>(text, out_lens);
  k_lstm  <<<256, 256, 0, stream>>>(text, embed, Wx, Wh, bias, hs, cnt);
  k_logits<<<256, 128, 0, stream>>>(hs, Wd, bd, out_logits);
  k_crf   <<<B_SZ, 64, 0, stream>>>(out_logits, labels, trans, out_lens, out_ll);
}

// Round 2
// 1730.682 us; speedup vs baseline: 7.1623x; 7.1623x over previous
//
#include <hip/hip_runtime.h>
#include <hip/hip_bf16.h>

#define V_SZ 100000
#define E_SZ 128
#define H_SZ 512
#define L_SZ 9
#define B_SZ 64
#define T_SZ 512
#define G4   (4*H_SZ)

#define LOGITS_N (B_SZ*T_SZ*L_SZ)            // 294912
#define HS_BYTES ((size_t)B_SZ*T_SZ*H_SZ*2)  // 33554432

typedef short bf16x8 __attribute__((ext_vector_type(8)));
typedef float f32x4  __attribute__((ext_vector_type(4)));

static __device__ __forceinline__ unsigned short f2bf(float x){
  unsigned int u = __builtin_bit_cast(unsigned int, x);
  unsigned int r = (u + 0x7fffu + ((u >> 16) & 1u)) >> 16;
  return (unsigned short)r;
}
static __device__ __forceinline__ float bf2f(unsigned short b){
  unsigned int u = ((unsigned int)b) << 16;
  return __builtin_bit_cast(float, u);
}
static __device__ __forceinline__ float sig_f(float x){
  return 1.f / (1.f + __expf(-x));
}
static __device__ __forceinline__ float tanh_f(float x){
  float a = fabsf(x);
  float e = __expf(-2.f * a);
  float t = (1.f - e) / (1.f + e);
  return copysignf(t, x);
}

// ---------------- lens ----------------
__global__ void k_lens(const int* __restrict__ text, float* __restrict__ out_lens){
  int b = blockIdx.x;
  int c = 0;
  for (int t = threadIdx.x; t < T_SZ; t += 256)
    c += (text[b*T_SZ + t] != 0);
  for (int off = 32; off; off >>= 1) c += __shfl_down(c, off, 64);
  __shared__ int sred[4];
  int w = threadIdx.x >> 6;
  if ((threadIdx.x & 63) == 0) sred[w] = c;
  __syncthreads();
  if (threadIdx.x == 0)
    out_lens[b] = (float)(sred[0] + sred[1] + sred[2] + sred[3]);
}

// ---------------- fused embed + xg + LSTM recurrence ----------------
// 8 groups x 32 blocks. Group g owns sequences [g*8, g*8+8); block j owns
// h-columns [j*16, j*16+16). Weights live in VGPRs as bf16 MFMA B-frags.
// Cross-block exchange: relaxed agent-scope (sc1 -> LLC) stores/loads +
// per-(step,block) flag array. NO acquire fences / threadfence in the loop.
__global__ __launch_bounds__(256, 1)
void k_lstm(const int* __restrict__ text, const float* __restrict__ embed,
            const float* __restrict__ Wx, const float* __restrict__ Wh,
            const float* __restrict__ bias, unsigned short* __restrict__ hs,
            int* __restrict__ flags)
{
  const int g    = blockIdx.x & 7;     // group (intended XCD under round-robin)
  const int j    = blockIdx.x >> 3;    // 0..31 block-in-group
  const int n0   = j * 16;             // owned h-columns [n0, n0+16)
  const int tid  = threadIdx.x;
  const int w    = tid >> 6;           // wave = gate quadrant (i,f,cg,o)
  const int lane = tid & 63;
  const int q    = lane >> 4;
  const int l16  = lane & 15;

  __shared__ unsigned short h_lds[16*512];   // 16 KB, XOR-swizzled, rows 8-15 zero
  __shared__ unsigned short x_lds[16*128];   // 4 KB, XOR-swizzled, rows 8-15 zero
  __shared__ float gate_lds[4][8][16];       // 2 KB

  for (int i = tid; i < 16*512; i += 256) h_lds[i] = 0;
  for (int i = tid; i < 16*128; i += 256) x_lds[i] = 0;

  // Preload weight B-frags (bf16). B elem jj of k-chunk kk:
  // W[(kk*32 + q*8 + jj)][gcol] — same (q,jj)->k map as the A-side LDS reads.
  const int gcol = w * H_SZ + n0 + l16;
  bf16x8 Whf[16];
#pragma unroll
  for (int kk = 0; kk < 16; ++kk){
    bf16x8 v;
#pragma unroll
    for (int jj = 0; jj < 8; ++jj)
      v[jj] = (short)f2bf(Wh[(long)(kk*32 + q*8 + jj)*G4 + gcol]);
    Whf[kk] = v;
  }
  bf16x8 Wxf[4];
#pragma unroll
  for (int kk = 0; kk < 4; ++kk){
    bf16x8 v;
#pragma unroll
    for (int jj = 0; jj < 8; ++jj)
      v[jj] = (short)f2bf(Wx[(long)(kk*32 + q*8 + jj)*G4 + gcol]);
    Wxf[kk] = v;
  }
  const float biasv = bias[gcol];

  // c-state: wave 0 only; thread (r = tid>>3, cols c2, c2+1)
  float cs0 = 0.f, cs1 = 0.f;
  const int gr = tid >> 3;            // 0..7 (valid for tid<64)
  const int gc2 = (tid & 7) * 2;      // 0,2,..,14

  __syncthreads();

  for (int t = 0; t < T_SZ; ++t){
    // ---- stage x_t (embed gather -> bf16 -> swizzled LDS) ----
    {
      int xr = tid >> 5;                    // 0..7 (batch row)
      int c4 = (tid & 31) * 4;              // f32 column
      int idx = text[(g*8 + xr)*T_SZ + t];
      const float4 xv = *(const float4*)(embed + (long)idx*E_SZ + c4);
      int cb = c4 * 2;                      // byte col
      unsigned short* p = (unsigned short*)((char*)x_lds + xr*256 + (cb ^ (xr << 4)));
      p[0] = f2bf(xv.x); p[1] = f2bf(xv.y); p[2] = f2bf(xv.z); p[3] = f2bf(xv.w);
    }

    if (t > 0){
      // ---- wait for all 32 producer flags of step t-1 (relaxed, parallel) ----
      if (tid < 64){
        const int* fl = flags + (g*T_SZ + (t-1))*32;
        int it = 0;
        for (;;){
          int f = 1;
          if (lane < 32)
            f = __hip_atomic_load(&fl[lane], __ATOMIC_RELAXED, __HIP_MEMORY_SCOPE_AGENT);
          if (__all(f != 0)) break;
          if (++it > (1 << 20)) break;     // hang safeguard
        }
      }
      __syncthreads();   // B1: flags observed; prev-iter LDS reads long done

      // ---- stage h_{t-1}: 8 rows x 512 bf16 via LLC-direct 8B loads ----
#pragma unroll
      for (int c = 0; c < 4; ++c){
        int chunk = tid + 256*c;            // 0..1023
        int hr    = chunk >> 7;             // 0..7
        int k4    = chunk & 127;            // 8B chunk -> cols k4*4
        unsigned long long v = __hip_atomic_load(
            (const unsigned long long*)(hs + ((long)(g*8 + hr)*T_SZ + (t-1))*H_SZ + k4*4),
            __ATOMIC_RELAXED, __HIP_MEMORY_SCOPE_AGENT);
        int cb = k4 * 8;
        *(unsigned long long*)((char*)h_lds + hr*1024 + (cb ^ (hr << 4))) = v;
      }
    }
    __syncthreads();     // B2: staging complete -> MFMA may read

    // ---- MFMA: C = x_t @ Wx (+ h_{t-1} @ Wh) ----
    f32x4 acc0 = {0.f,0.f,0.f,0.f}, acc1 = {0.f,0.f,0.f,0.f};
#pragma unroll
    for (int kk = 0; kk < 4; ++kk){
      bf16x8 a = *(const bf16x8*)((const char*)x_lds + l16*256 + ((kk*64 + q*16) ^ (l16 << 4)));
      if (kk & 1) acc1 = __builtin_amdgcn_mfma_f32_16x16x32_bf16(a, Wxf[kk], acc1, 0, 0, 0);
      else        acc0 = __builtin_amdgcn_mfma_f32_16x16x32_bf16(a, Wxf[kk], acc0, 0, 0, 0);
    }
    if (t > 0){
#pragma unroll
      for (int kk = 0; kk < 16; ++kk){
        bf16x8 a = *(const bf16x8*)((const char*)h_lds + l16*1024 + ((kk*64 + q*16) ^ (l16 << 4)));
        if (kk & 1) acc1 = __builtin_amdgcn_mfma_f32_16x16x32_bf16(a, Whf[kk], acc1, 0, 0, 0);
        else        acc0 = __builtin_amdgcn_mfma_f32_16x16x32_bf16(a, Whf[kk], acc0, 0, 0, 0);
      }
    }
    // C/D layout: col = lane&15, row = (lane>>4)*4 + reg  (rows 0..7 valid)
#pragma unroll
    for (int rg = 0; rg < 4; ++rg){
      int row = q*4 + rg;
      if (row < 8) gate_lds[w][row][l16] = acc0[rg] + acc1[rg] + biasv;
    }
    __syncthreads();     // B3: gate_lds ready -> wave 0 consumes

    // ---- gates -> (c,h); wave 0 only; publish h + flag (relaxed, sc1) ----
    if (tid < 64){
      float gi0 = gate_lds[0][gr][gc2],   gi1 = gate_lds[0][gr][gc2+1];
      float gf0 = gate_lds[1][gr][gc2],   gf1 = gate_lds[1][gr][gc2+1];
      float gg0 = gate_lds[2][gr][gc2],   gg1 = gate_lds[2][gr][gc2+1];
      float go0 = gate_lds[3][gr][gc2],   go1 = gate_lds[3][gr][gc2+1];
      cs0 = sig_f(gf0)*cs0 + sig_f(gi0)*tanh_f(gg0);
      cs1 = sig_f(gf1)*cs1 + sig_f(gi1)*tanh_f(gg1);
      float h0 = sig_f(go0)*tanh_f(cs0);
      float h1 = sig_f(go1)*tanh_f(cs1);
      unsigned int pk = (unsigned int)f2bf(h0) | ((unsigned int)f2bf(h1) << 16);
      __hip_atomic_store(
          (unsigned int*)(hs + ((long)(g*8 + gr)*T_SZ + t)*H_SZ + n0 + gc2), pk,
          __ATOMIC_RELAXED, __HIP_MEMORY_SCOPE_AGENT);
      asm volatile("s_waitcnt vmcnt(0)" ::: "memory");   // wave0's h stores at LLC
      if (tid == 0)
        __hip_atomic_store(&flags[(g*T_SZ + t)*32 + j], 1,
                           __ATOMIC_RELAXED, __HIP_MEMORY_SCOPE_AGENT);
    }
    // waves 1-3 run ahead to stage x_{t+1}; B1/B2 re-synchronize.
  }
}

// ---------------- logits = hs @ Wd + bd ----------------
__global__ void k_logits(const unsigned short* __restrict__ hs,
                         const float* __restrict__ Wd, const float* __restrict__ bd,
                         float* __restrict__ out)
{
  __shared__ float wd_s[H_SZ*L_SZ];
  __shared__ float bd_s[L_SZ];
  for (int i = threadIdx.x; i < H_SZ*L_SZ; i += 128) wd_s[i] = Wd[i];
  if (threadIdx.x < L_SZ) bd_s[threadIdx.x] = bd[threadIdx.x];
  __syncthreads();

  long row = (long)blockIdx.x*128 + threadIdx.x;   // 0..32767
  const unsigned short* hp = hs + row*H_SZ;
  float acc[9];
#pragma unroll
  for (int jj = 0; jj < 9; ++jj) acc[jj] = 0.f;
  for (int k = 0; k < H_SZ; k += 8){
    uint4 v = *(const uint4*)(hp + k);
    const unsigned short* u = (const unsigned short*)&v;
#pragma unroll
    for (int l = 0; l < 8; ++l){
      float hf = bf2f(u[l]);
#pragma unroll
      for (int jj = 0; jj < 9; ++jj)
        acc[jj] = fmaf(hf, wd_s[(k + l)*L_SZ + jj], acc[jj]);
    }
  }
  float* op = out + row*L_SZ;
#pragma unroll
  for (int jj = 0; jj < 9; ++jj) op[jj] = acc[jj] + bd_s[jj];
}

// ---------------- CRF: score + forward algorithm ----------------
__global__ void k_crf(const float* __restrict__ logits, const int* __restrict__ labels,
                      const float* __restrict__ trans, const float* __restrict__ lensf,
                      float* __restrict__ out_ll)
{
  int b = blockIdx.x;
  int lane = threadIdx.x;             // 64 threads = 1 wave
  int len = (int)lensf[b];
  const float* lg  = logits + (long)b*T_SZ*L_SZ;
  const int*   lab = labels + b*T_SZ;

  float s = 0.f;
  for (int t = lane; t < T_SZ; t += 64){
    if (t < len){
      s += lg[t*L_SZ + lab[t]];
      if (t >= 1) s += trans[lab[t-1]*L_SZ + lab[t]];
    }
  }
  for (int off = 32; off; off >>= 1) s += __shfl_down(s, off, 64);

  float tr[9];
#pragma unroll
  for (int i = 0; i < 9; ++i) tr[i] = (lane < 9) ? trans[i*L_SZ + lane] : 0.f;
  float alpha = (lane < 9) ? lg[lane] : -1e30f;

  for (int t = 1; t < T_SZ; ++t){
    float tmp[9];
    float m = -1e30f;
#pragma unroll
    for (int i = 0; i < 9; ++i){
      float ai = __shfl(alpha, i, 64);
      tmp[i] = ai + tr[i];
      m = fmaxf(m, tmp[i]);
    }
    float e = 0.f;
#pragma unroll
    for (int i = 0; i < 9; ++i) e += __expf(tmp[i] - m);
    float lgv = (lane < 9) ? lg[t*L_SZ + lane] : 0.f;
    float nv = m + __logf(e) + lgv;
    if (t < len && lane < 9) alpha = nv;
  }

  float mm = (lane < 9) ? alpha : -1e30f;
  for (int off = 8; off; off >>= 1) mm = fmaxf(mm, __shfl_down(mm, off, 64));
  mm = __shfl(mm, 0, 64);
  float ee = (lane < 9) ? __expf(alpha - mm) : 0.f;
  for (int off = 8; off; off >>= 1) ee += __shfl_down(ee, off, 64);
  if (lane == 0) out_ll[b] = s - (mm + __logf(ee));
}

extern "C" void kernel_launch(void* const* d_in, const int* in_sizes, int n_in,
                              void* d_out, int out_size, void* d_ws, size_t ws_size,
                              hipStream_t stream)
{
  const int*   text   = (const int*)  d_in[0];
  const int*   labels = (const int*)  d_in[1];
  const float* embed  = (const float*)d_in[2];
  const float* Wx     = (const float*)d_in[3];
  const float* Wh     = (const float*)d_in[4];
  const float* bias   = (const float*)d_in[5];
  const float* Wd     = (const float*)d_in[6];
  const float* bd     = (const float*)d_in[7];
  const float* trans  = (const float*)d_in[8];

  float* out        = (float*)d_out;
  float* out_logits = out;
  float* out_lens   = out + LOGITS_N;
  float* out_ll     = out + LOGITS_N + B_SZ;

  unsigned short* hs = (unsigned short*)d_ws;
  int* flags = (int*)((char*)d_ws + HS_BYTES);

  hipMemsetAsync(flags, 0, 8*T_SZ*32*sizeof(int), stream);
  k_lens  <<<B_SZ, 256, 0, stream>>>(text, out_lens);
  k_lstm  <<<256, 256, 0, stream>>>(text, embed, Wx, Wh, bias, hs, flags);
  k_logits<<<256, 128, 0, stream>>>(hs, Wd, bd, out_logits);
  k_crf   <<<B_SZ, 64, 0, stream>>>(out_logits, labels, trans, out_lens, out_ll);
}